// Round 10
// baseline (45.040 us; speedup 1.0000x reference)
//
#include <hip/hip_runtime.h>
#include <math.h>

#define LN_EPS 1e-5f

// Problem constants (fixed by setup_inputs): N=10, K=5, Q=5, H=256, Qtot=50
constexpr int Nn  = 10;
constexpr int Kk  = 5;
constexpr int Hh  = 256;
constexpr int QT  = 50;
constexpr int NP1 = 11;

// ---------- DPP-based reductions (VALU pipe; zero DS-pipe ops) ----------
template<int CTRL, int RM>
__device__ __forceinline__ float dpp_term(float x) {
    return __int_as_float(__builtin_amdgcn_update_dpp(
        0, __float_as_int(x), CTRL, RM, 0xf, true));   // bound_ctrl: OOB -> 0
}
// wave sum accumulated into lane 63 (6 DPP adds)
__device__ __forceinline__ float sum64_lane63(float v) {
    v += dpp_term<0x111, 0xf>(v);   // row_shr:1
    v += dpp_term<0x112, 0xf>(v);   // row_shr:2
    v += dpp_term<0x114, 0xf>(v);   // row_shr:4
    v += dpp_term<0x118, 0xf>(v);   // row_shr:8
    v += dpp_term<0x142, 0xa>(v);   // row_bcast:15 -> rows 1,3
    v += dpp_term<0x143, 0xc>(v);   // row_bcast:31 -> rows 2,3 (lane63 = total)
    return v;
}
__device__ __forceinline__ float rdlane(float v, int l) {
    return __int_as_float(__builtin_amdgcn_readlane(__float_as_int(v), l));
}
__device__ __forceinline__ float wave64_sum_bcast(float v) {
    return rdlane(sum64_lane63(v), 63);
}

// One batch per 1024-thread block (16 waves). 3 barriers.
// A  (waves 0-9):  support stream: LN inline (stats->LDS), M, ||M||^2, scores.
// C  (ALL 16 waves, wave-per-query q=i*16+wave): load row once (wave64 layout,
//     4 floats/lane), fused LN stats, ny->LDS, dots vs M with M-fragment read
//     ONCE per n and reused across the wave's 3-4 queries (LDS-pipe fix:
//     ds_read_b128 count 1250 -> 320 per CU), argmin(nM-2p), wq/cq/counts.
//     B (wave 15, lanes 0-4): per-k softmax over N of support scores.
// E  (waves 0-9):  rectified prototype (ballot loop, readlane bcast), ||p||^2.
// F  (ALL 16 waves, wave-per-query): reload+LN from qstat, dots vs proto
//     (fragment reuse), logits assembled via lane==n cndmask selects
//     (d is wave-uniform after broadcast reduce), lanes 0-11 store.
// NOTE: nothing register-live across barriers (round-4 spill lesson).
__global__ __launch_bounds__(1024, 8) void proto_rectify_fused(
    const float* __restrict__ support, const float* __restrict__ query,
    const float* __restrict__ gamma,   const float* __restrict__ beta,
    float* __restrict__ out, int B)
{
    const int b    = blockIdx.x;
    const int tid  = threadIdx.x;
    const int lane = tid & 63;
    const int wave = tid >> 6;   // 0..15

    __shared__ float g_s[Hh], bt_s[Hh];
    __shared__ float M_s[Nn][Hh];
    __shared__ float proto_s[Nn][Hh];
    __shared__ float nM_s[Nn], np_s[Nn];
    __shared__ float ny_s[QT];
    __shared__ float score_s[Nn * Kk];
    __shared__ float wsup_s[Nn * Kk];
    __shared__ float wq_s[QT];
    __shared__ int   cq_s[QT];
    __shared__ float sstat_s[Nn * Kk][2];  // support row: mu, rstd
    __shared__ float qstat_s[QT][2];       // query row:   mu, rstd
    __shared__ int   cnt_s[Nn];

    const float* supB = support + (size_t)b * (Nn * Kk * Hh);
    const float* qryB = query   + (size_t)b * (QT * Hh);

    // LDS preload runs concurrently with phase A (consumed only after sync 1)
    if (tid < Hh)          g_s[tid]       = gamma[tid];
    else if (tid < 2 * Hh) bt_s[tid - Hh] = beta[tid - Hh];
    if (tid < Nn)          cnt_s[tid]     = 0;

    // ---------------- Phase A: support only (waves 0-9) ----------------
    if (wave < Nn) {
        const int n = wave;
        const float4 g4 = *reinterpret_cast<const float4*>(gamma + lane * 4); // L1
        const float4 b4 = *reinterpret_cast<const float4*>(beta  + lane * 4);
        const float* rows = supB + (size_t)n * Kk * Hh;

        float y[Kk][4];
#pragma unroll
        for (int k = 0; k < Kk; ++k) {
            const float4 x = *reinterpret_cast<const float4*>(rows + k * Hh + lane * 4);
            float s  = x.x + x.y + x.z + x.w;
            float ss = x.x * x.x + x.y * x.y + x.z * x.z + x.w * x.w;
            s  = wave64_sum_bcast(s);
            ss = wave64_sum_bcast(ss);
            const float mu   = s * (1.0f / (float)Hh);
            const float rstd = rsqrtf(ss * (1.0f / (float)Hh) - mu * mu + LN_EPS);
            if (lane == 0) { sstat_s[n * Kk + k][0] = mu; sstat_s[n * Kk + k][1] = rstd; }
            y[k][0] = (x.x - mu) * rstd * g4.x + b4.x;
            y[k][1] = (x.y - mu) * rstd * g4.y + b4.y;
            y[k][2] = (x.z - mu) * rstd * g4.z + b4.z;
            y[k][3] = (x.w - mu) * rstd * g4.w + b4.w;
        }
        float Mv[4];
#pragma unroll
        for (int i = 0; i < 4; ++i)
            Mv[i] = (y[0][i] + y[1][i] + y[2][i] + y[3][i] + y[4][i]) / 5.0f;
        *reinterpret_cast<float4*>(&M_s[n][lane * 4]) =
            make_float4(Mv[0], Mv[1], Mv[2], Mv[3]);

        float pm = Mv[0] * Mv[0];
        pm = fmaf(Mv[1], Mv[1], pm); pm = fmaf(Mv[2], Mv[2], pm); pm = fmaf(Mv[3], Mv[3], pm);
        pm = sum64_lane63(pm);
        if (lane == 63) nM_s[n] = pm;

#pragma unroll
        for (int k = 0; k < Kk; ++k) {
            float p = y[k][0] * Mv[0];
            p = fmaf(y[k][1], Mv[1], p); p = fmaf(y[k][2], Mv[2], p); p = fmaf(y[k][3], Mv[3], p);
            p = sum64_lane63(p);
            if (lane == 63) score_s[n * Kk + k] = p;
        }
    }
    __syncthreads();

    // ---------------- C: wave-per-query (all 16 waves) + B (wave 15) --------
    {
        const float4 g4 = *reinterpret_cast<const float4*>(g_s  + lane * 4);
        const float4 b4 = *reinterpret_cast<const float4*>(bt_s + lane * 4);
        const float nmv = (lane < Nn) ? nM_s[lane] : 0.f;

        float4 ya[4];                       // this wave's LN'd queries (4/lane)
#pragma unroll
        for (int i = 0; i < 4; ++i) {
            const int q = i * 16 + wave;    // wave-uniform bound
            if (q < QT) {
                const float4 x = *reinterpret_cast<const float4*>(
                    qryB + (size_t)q * Hh + lane * 4);
                float s  = x.x + x.y + x.z + x.w;
                float ss = fmaf(x.x, x.x, fmaf(x.y, x.y, fmaf(x.z, x.z, x.w * x.w)));
                s  = wave64_sum_bcast(s);
                ss = wave64_sum_bcast(ss);
                const float mu   = s * (1.0f / (float)Hh);
                const float rstd = rsqrtf(ss * (1.0f / (float)Hh) - mu * mu + LN_EPS);
                ya[i].x = (x.x - mu) * rstd * g4.x + b4.x;
                ya[i].y = (x.y - mu) * rstd * g4.y + b4.y;
                ya[i].z = (x.z - mu) * rstd * g4.z + b4.z;
                ya[i].w = (x.w - mu) * rstd * g4.w + b4.w;
                float ny = fmaf(ya[i].x, ya[i].x, fmaf(ya[i].y, ya[i].y,
                           fmaf(ya[i].z, ya[i].z, ya[i].w * ya[i].w)));
                ny = sum64_lane63(ny);
                if (lane == 63) ny_s[q] = ny;
                if (lane == 0)  { qstat_s[q][0] = mu; qstat_s[q][1] = rstd; }
            }
        }

        float bestd[4], bestdot[4]; int bestn[4];
#pragma unroll
        for (int i = 0; i < 4; ++i) { bestd[i] = INFINITY; bestdot[i] = 0.f; bestn[i] = 0; }

#pragma unroll
        for (int n = 0; n < Nn; ++n) {
            const float4 mv = *reinterpret_cast<const float4*>(&M_s[n][lane * 4]);
            const float  nm = rdlane(nmv, n);
#pragma unroll
            for (int i = 0; i < 4; ++i) {
                const int q = i * 16 + wave;
                if (q < QT) {
                    float p = fmaf(ya[i].x, mv.x, fmaf(ya[i].y, mv.y,
                              fmaf(ya[i].z, mv.z, ya[i].w * mv.w)));
                    p = wave64_sum_bcast(p);
                    const float d = nm - 2.0f * p;     // argmin drops ny (const/q)
                    if (d < bestd[i]) { bestd[i] = d; bestn[i] = n; bestdot[i] = p; }
                }
            }
        }
#pragma unroll
        for (int i = 0; i < 4; ++i) {
            const int q = i * 16 + wave;
            if (q < QT && lane == 0) {
                const float sc  = bestdot[i];          // <q, M_bestn>
                const float mx  = fmaxf(sc, 0.f);
                const float e   = expf(sc - mx);
                const float den = e + (float)(Nn - 1) * expf(-mx);
                wq_s[q] = e / den;
                cq_s[q] = bestn[i];
                atomicAdd(&cnt_s[bestn[i]], 1);
            }
        }
        // B: per-k softmax over N of support scores (wave 15, lanes 0..K-1)
        if (wave == 15 && lane < Kk) {
            const int k = lane;
            float mx = -INFINITY;
#pragma unroll
            for (int n = 0; n < Nn; ++n) mx = fmaxf(mx, score_s[n * Kk + k]);
            float e[Nn]; float den = 0.f;
#pragma unroll
            for (int n = 0; n < Nn; ++n) { e[n] = expf(score_s[n * Kk + k] - mx); den += e[n]; }
#pragma unroll
            for (int n = 0; n < Nn; ++n) wsup_s[n * Kk + k] = e[n] / den;
        }
    }
    __syncthreads();

    // ---------------- E (waves 0-9): rectified prototype ----------------
    if (wave < Nn) {
        const int n = wave;
        const float4 g4 = *reinterpret_cast<const float4*>(g_s  + lane * 4);
        const float4 b4 = *reinterpret_cast<const float4*>(bt_s + lane * 4);
        const float* rows = supB + (size_t)n * Kk * Hh;

        float acc[4] = {0.f, 0.f, 0.f, 0.f};
#pragma unroll
        for (int k = 0; k < Kk; ++k) {
            const float w    = wsup_s[n * Kk + k];
            const float mu   = sstat_s[n * Kk + k][0];
            const float rstd = sstat_s[n * Kk + k][1];
            const float4 x = *reinterpret_cast<const float4*>(rows + k * Hh + lane * 4);
            acc[0] = fmaf(w, (x.x - mu) * rstd * g4.x + b4.x, acc[0]);
            acc[1] = fmaf(w, (x.y - mu) * rstd * g4.y + b4.y, acc[1]);
            acc[2] = fmaf(w, (x.z - mu) * rstd * g4.z + b4.z, acc[2]);
            acc[3] = fmaf(w, (x.w - mu) * rstd * g4.w + b4.w, acc[3]);
        }
        // ballot-compressed query rectification; per-q scalars via readlane (VALU)
        int myc = -1; float myw = 0.f, mymu = 0.f, myr = 0.f;
        if (lane < QT) {
            myc  = cq_s[lane]; myw = wq_s[lane];
            mymu = qstat_s[lane][0]; myr = qstat_s[lane][1];
        }
        unsigned long long mask = __ballot(lane < QT && myc == n);
        while (mask) {
            const int q = __ffsll(mask) - 1;
            mask &= mask - 1;
            const float w    = rdlane(myw,  q);
            const float mu   = rdlane(mymu, q);
            const float rstd = rdlane(myr,  q);
            const float4 x = *reinterpret_cast<const float4*>(qryB + (size_t)q * Hh + lane * 4);
            acc[0] = fmaf(w, (x.x - mu) * rstd * g4.x + b4.x, acc[0]);
            acc[1] = fmaf(w, (x.y - mu) * rstd * g4.y + b4.y, acc[1]);
            acc[2] = fmaf(w, (x.z - mu) * rstd * g4.z + b4.z, acc[2]);
            acc[3] = fmaf(w, (x.w - mu) * rstd * g4.w + b4.w, acc[3]);
        }
        const float inv = 1.0f / (float)(Kk + cnt_s[n]);
        float pv[4];
#pragma unroll
        for (int i = 0; i < 4; ++i) pv[i] = acc[i] * inv;
        *reinterpret_cast<float4*>(&proto_s[n][lane * 4]) =
            make_float4(pv[0], pv[1], pv[2], pv[3]);
        float pp = pv[0] * pv[0];
        pp = fmaf(pv[1], pv[1], pp); pp = fmaf(pv[2], pv[2], pp); pp = fmaf(pv[3], pv[3], pp);
        pp = sum64_lane63(pp);
        if (lane == 63) np_s[n] = pp;
    }
    __syncthreads();

    // ---------------- F: wave-per-query (all 16 waves) ----------------
    {
        const float4 g4 = *reinterpret_cast<const float4*>(g_s  + lane * 4);
        const float4 b4 = *reinterpret_cast<const float4*>(bt_s + lane * 4);
        const float npv = (lane < Nn) ? np_s[lane] : 0.f;

        float4 ya[4]; float nyq[4];
#pragma unroll
        for (int i = 0; i < 4; ++i) {
            const int q = i * 16 + wave;
            if (q < QT) {
                const float mu   = qstat_s[q][0];
                const float rstd = qstat_s[q][1];
                const float4 x = *reinterpret_cast<const float4*>(
                    qryB + (size_t)q * Hh + lane * 4);
                ya[i].x = (x.x - mu) * rstd * g4.x + b4.x;
                ya[i].y = (x.y - mu) * rstd * g4.y + b4.y;
                ya[i].z = (x.z - mu) * rstd * g4.z + b4.z;
                ya[i].w = (x.w - mu) * rstd * g4.w + b4.w;
                nyq[i] = ny_s[q];
            }
        }
        float ov[4], maxd[4], bestd[4]; int bestn[4];
#pragma unroll
        for (int i = 0; i < 4; ++i) { ov[i] = 0.f; maxd[i] = -INFINITY;
                                      bestd[i] = INFINITY; bestn[i] = 0; }
#pragma unroll
        for (int n = 0; n < Nn; ++n) {
            const float4 pv = *reinterpret_cast<const float4*>(&proto_s[n][lane * 4]);
            const float  np = rdlane(npv, n);
#pragma unroll
            for (int i = 0; i < 4; ++i) {
                const int q = i * 16 + wave;
                if (q < QT) {
                    float p = fmaf(ya[i].x, pv.x, fmaf(ya[i].y, pv.y,
                              fmaf(ya[i].z, pv.z, ya[i].w * pv.w)));
                    p = wave64_sum_bcast(p);
                    const float d = nyq[i] + np - 2.0f * p;
                    if (lane == n) ov[i] = d;          // cndmask: d is wave-uniform
                    maxd[i] = fmaxf(maxd[i], d);
                    if (d < bestd[i]) { bestd[i] = d; bestn[i] = n; }
                }
            }
        }
#pragma unroll
        for (int i = 0; i < 4; ++i) {
            const int q = i * 16 + wave;
            if (q < QT) {
                if (lane == Nn) ov[i] = maxd[i] + 1.0f;      // slot N: min(logits)-1
                float* o = out + ((size_t)b * QT + q) * NP1;
                if (lane <= Nn) o[lane] = -ov[i];
                if (lane == Nn + 1)
                    out[(size_t)B * QT * NP1 + (size_t)b * QT + q] = (float)bestn[i];
            }
        }
    }
}

extern "C" void kernel_launch(void* const* d_in, const int* in_sizes, int n_in,
                              void* d_out, int out_size, void* d_ws, size_t ws_size,
                              hipStream_t stream) {
    const float* support = (const float*)d_in[0];
    const float* query   = (const float*)d_in[1];
    const float* gamma   = (const float*)d_in[2];
    const float* beta    = (const float*)d_in[3];
    float* out = (float*)d_out;

    const int B = in_sizes[0] / (Nn * Kk * Hh);   // 512
    proto_rectify_fused<<<B, 1024, 0, stream>>>(support, query, gamma, beta, out, B);
}

// Round 11
// 33.019 us; speedup vs baseline: 1.3641x; 1.3641x over previous
//
#include <hip/hip_runtime.h>
#include <math.h>

#define LN_EPS 1e-5f

// Problem constants (fixed by setup_inputs): N=10, K=5, Q=5, H=256, Qtot=50
constexpr int Nn  = 10;
constexpr int Kk  = 5;
constexpr int Hh  = 256;
constexpr int QT  = 50;
constexpr int NP1 = 11;

// ---------- DPP-based reductions (VALU pipe; zero DS-pipe ops) ----------
template<int CTRL, int RM>
__device__ __forceinline__ float dpp_term(float x) {
    return __int_as_float(__builtin_amdgcn_update_dpp(
        0, __float_as_int(x), CTRL, RM, 0xf, true));   // bound_ctrl: OOB -> 0
}
// broadcast sum across each 16-lane group (4 DPP adds)
__device__ __forceinline__ float sum16_bcast(float v) {
    v += dpp_term<0xB1,  0xf>(v);   // quad_perm [1,0,3,2]
    v += dpp_term<0x4E,  0xf>(v);   // quad_perm [2,3,0,1]
    v += dpp_term<0x124, 0xf>(v);   // row_ror:4
    v += dpp_term<0x128, 0xf>(v);   // row_ror:8 -> full 16-sum, all lanes
    return v;
}
// wave sum accumulated into lane 63 (6 DPP adds)
__device__ __forceinline__ float sum64_lane63(float v) {
    v += dpp_term<0x111, 0xf>(v);   // row_shr:1
    v += dpp_term<0x112, 0xf>(v);   // row_shr:2
    v += dpp_term<0x114, 0xf>(v);   // row_shr:4
    v += dpp_term<0x118, 0xf>(v);   // row_shr:8
    v += dpp_term<0x142, 0xa>(v);   // row_bcast:15 -> rows 1,3
    v += dpp_term<0x143, 0xc>(v);   // row_bcast:31 -> rows 2,3 (lane63 = total)
    return v;
}
__device__ __forceinline__ float rdlane(float v, int l) {
    return __int_as_float(__builtin_amdgcn_readlane(__float_as_int(v), l));
}
__device__ __forceinline__ float wave64_sum_bcast(float v) {
    return rdlane(sum64_lane63(v), 63);
}

// One batch per 512-thread block (8 waves), 4 blocks/CU (latency hiding:
// 4 independent barrier-desynchronized blocks per CU vs 2 at 1024 threads).
// 3 barriers. Same phase bodies as the 28.6us round-8 kernel, loops strided:
// A (waves 0-7, n=wave,wave+8): support LN inline (stats->LDS), M, ||M||^2, scores.
// C (groups 0-31, q=grp,grp+32): R8 grp16 body per query (load once, fused LN
//    stats, ny->LDS, argmin(nM-2p), wq/cq/counts).
// E (waves 0-7, n=wave,wave+8): support-score softmax computed INLINE (lanes
//    0-4, ~30 ops, replaces the B phase + wsup LDS round trip), weighted
//    accumulation + ballot-compressed query loop, ||p||^2.
// F (groups 0-31, q=grp,grp+32): reload+LN from qstat, d=ny+np-2p, logits/pred.
// NOTE: nothing register-live across barriers (round-4 spill lesson).
__global__ __launch_bounds__(512, 8) void proto_rectify_fused(
    const float* __restrict__ support, const float* __restrict__ query,
    const float* __restrict__ gamma,   const float* __restrict__ beta,
    float* __restrict__ out, int B)
{
    const int b    = blockIdx.x;
    const int tid  = threadIdx.x;
    const int lane = tid & 63;
    const int wave = tid >> 6;   // 0..7
    const int grp  = tid >> 4;   // 0..31
    const int sub  = tid & 15;

    __shared__ float g_s[Hh], bt_s[Hh];
    __shared__ float M_s[Nn][Hh];
    __shared__ float proto_s[Nn][Hh];
    __shared__ float nM_s[Nn], np_s[Nn];
    __shared__ float ny_s[QT];
    __shared__ float score_s[Nn * Kk];
    __shared__ float wq_s[QT];
    __shared__ int   cq_s[QT];
    __shared__ float sstat_s[Nn * Kk][2];  // support row: mu, rstd
    __shared__ float qstat_s[QT][2];       // query row:   mu, rstd
    __shared__ int   cnt_s[Nn];

    const float* supB = support + (size_t)b * (Nn * Kk * Hh);
    const float* qryB = query   + (size_t)b * (QT * Hh);

    // LDS preload runs concurrently with phase A (consumed only after sync 1)
    if (tid < Hh) g_s[tid] = gamma[tid];
    else          bt_s[tid - Hh] = beta[tid - Hh];   // 512 threads cover both
    if (tid < Nn) cnt_s[tid] = 0;

    // ---------------- Phase A: support (waves 0-7, strided n) ----------------
    {
        const float4 g4 = *reinterpret_cast<const float4*>(gamma + lane * 4); // L1
        const float4 b4 = *reinterpret_cast<const float4*>(beta  + lane * 4);
        for (int n = wave; n < Nn; n += 8) {
            const float* rows = supB + (size_t)n * Kk * Hh;
            float y[Kk][4];
#pragma unroll
            for (int k = 0; k < Kk; ++k) {
                const float4 x = *reinterpret_cast<const float4*>(rows + k * Hh + lane * 4);
                float s  = x.x + x.y + x.z + x.w;
                float ss = x.x * x.x + x.y * x.y + x.z * x.z + x.w * x.w;
                s  = wave64_sum_bcast(s);
                ss = wave64_sum_bcast(ss);
                const float mu   = s * (1.0f / (float)Hh);
                const float rstd = rsqrtf(ss * (1.0f / (float)Hh) - mu * mu + LN_EPS);
                if (lane == 0) { sstat_s[n * Kk + k][0] = mu; sstat_s[n * Kk + k][1] = rstd; }
                y[k][0] = (x.x - mu) * rstd * g4.x + b4.x;
                y[k][1] = (x.y - mu) * rstd * g4.y + b4.y;
                y[k][2] = (x.z - mu) * rstd * g4.z + b4.z;
                y[k][3] = (x.w - mu) * rstd * g4.w + b4.w;
            }
            float Mv[4];
#pragma unroll
            for (int i = 0; i < 4; ++i)
                Mv[i] = (y[0][i] + y[1][i] + y[2][i] + y[3][i] + y[4][i]) / 5.0f;
            *reinterpret_cast<float4*>(&M_s[n][lane * 4]) =
                make_float4(Mv[0], Mv[1], Mv[2], Mv[3]);

            float pm = Mv[0] * Mv[0];
            pm = fmaf(Mv[1], Mv[1], pm); pm = fmaf(Mv[2], Mv[2], pm); pm = fmaf(Mv[3], Mv[3], pm);
            pm = sum64_lane63(pm);
            if (lane == 63) nM_s[n] = pm;

#pragma unroll
            for (int k = 0; k < Kk; ++k) {
                float p = y[k][0] * Mv[0];
                p = fmaf(y[k][1], Mv[1], p); p = fmaf(y[k][2], Mv[2], p); p = fmaf(y[k][3], Mv[3], p);
                p = sum64_lane63(p);
                if (lane == 63) score_s[n * Kk + k] = p;
            }
        }
    }
    __syncthreads();

    // ---------------- C: groups 0-31, queries q = grp, grp+32 ----------------
    {
        const float nmv = (lane < Nn) ? nM_s[lane] : 0.f;
#pragma unroll
        for (int it = 0; it < 2; ++it) {
            const int q = grp + it * 32;
            if (q < QT) {
                const float* row = qryB + (size_t)q * Hh;
                float y16[16];
                float s = 0.f, ss = 0.f;
#pragma unroll
                for (int c = 0; c < 4; ++c) {
                    const float4 x = *reinterpret_cast<const float4*>(row + c * 64 + sub * 4);
                    y16[c * 4 + 0] = x.x; y16[c * 4 + 1] = x.y;
                    y16[c * 4 + 2] = x.z; y16[c * 4 + 3] = x.w;
                    s  += x.x + x.y + x.z + x.w;
                    ss  = fmaf(x.x, x.x, ss); ss = fmaf(x.y, x.y, ss);
                    ss  = fmaf(x.z, x.z, ss); ss = fmaf(x.w, x.w, ss);
                }
                s  = sum16_bcast(s);
                ss = sum16_bcast(ss);
                const float mu   = s * (1.0f / (float)Hh);
                const float rstd = rsqrtf(ss * (1.0f / (float)Hh) - mu * mu + LN_EPS);
                if (sub == 0) { qstat_s[q][0] = mu; qstat_s[q][1] = rstd; }

#pragma unroll
                for (int c = 0; c < 4; ++c) {
                    const int h = c * 64 + sub * 4;
                    const float4 gg = *reinterpret_cast<const float4*>(g_s + h);
                    const float4 bb = *reinterpret_cast<const float4*>(bt_s + h);
                    y16[c * 4 + 0] = (y16[c * 4 + 0] - mu) * rstd * gg.x + bb.x;
                    y16[c * 4 + 1] = (y16[c * 4 + 1] - mu) * rstd * gg.y + bb.y;
                    y16[c * 4 + 2] = (y16[c * 4 + 2] - mu) * rstd * gg.z + bb.z;
                    y16[c * 4 + 3] = (y16[c * 4 + 3] - mu) * rstd * gg.w + bb.w;
                }
                float ny = 0.f;
#pragma unroll
                for (int j = 0; j < 16; ++j) ny = fmaf(y16[j], y16[j], ny);
                ny = sum16_bcast(ny);
                if (sub == 0) ny_s[q] = ny;

                // argmin_n (ny + nM - 2p) == argmin_n (nM - 2p)
                float bestd = INFINITY, bestdot = 0.f;
                int bestn = 0;
#pragma unroll
                for (int n = 0; n < Nn; ++n) {
                    float p = 0.f;
#pragma unroll
                    for (int c = 0; c < 4; ++c) {
                        const float4 mv = *reinterpret_cast<const float4*>(&M_s[n][c * 64 + sub * 4]);
                        p = fmaf(y16[c * 4 + 0], mv.x, p);
                        p = fmaf(y16[c * 4 + 1], mv.y, p);
                        p = fmaf(y16[c * 4 + 2], mv.z, p);
                        p = fmaf(y16[c * 4 + 3], mv.w, p);
                    }
                    p = sum16_bcast(p);
                    const float d = rdlane(nmv, n) - 2.0f * p;
                    if (d < bestd) { bestd = d; bestn = n; bestdot = p; }  // first-min
                }
                if (sub == 0) {
                    const float sc  = bestdot;             // <q, M_bestn>
                    const float mx  = fmaxf(sc, 0.f);
                    const float e   = expf(sc - mx);
                    const float den = e + (float)(Nn - 1) * expf(-mx);
                    wq_s[q] = e / den;
                    cq_s[q] = bestn;
                    atomicAdd(&cnt_s[bestn], 1);
                }
            }
        }
    }
    __syncthreads();

    // ---------------- E: waves 0-7, strided n; inline support softmax --------
    {
        const float4 g4 = *reinterpret_cast<const float4*>(g_s  + lane * 4);
        const float4 b4 = *reinterpret_cast<const float4*>(bt_s + lane * 4);
        // per-q rectification data (used by ballot loop; loop-invariant)
        int myc = -1; float myw = 0.f, mymu = 0.f, myr = 0.f;
        if (lane < QT) {
            myc  = cq_s[lane]; myw = wq_s[lane];
            mymu = qstat_s[lane][0]; myr = qstat_s[lane][1];
        }
        for (int n = wave; n < Nn; n += 8) {
            // inline B: lane k (0..K-1) computes softmax-over-N weight for (n,k)
            float wown = 0.f;
            if (lane < Kk) {
                float mx = -INFINITY;
#pragma unroll
                for (int nn = 0; nn < Nn; ++nn) mx = fmaxf(mx, score_s[nn * Kk + lane]);
                float den = 0.f, mye = 0.f;
#pragma unroll
                for (int nn = 0; nn < Nn; ++nn) {
                    const float e = expf(score_s[nn * Kk + lane] - mx);
                    den += e;
                    if (nn == n) mye = e;
                }
                wown = mye / den;
            }
            const float* rows = supB + (size_t)n * Kk * Hh;
            float acc[4] = {0.f, 0.f, 0.f, 0.f};
#pragma unroll
            for (int k = 0; k < Kk; ++k) {
                const float w    = rdlane(wown, k);
                const float mu   = sstat_s[n * Kk + k][0];
                const float rstd = sstat_s[n * Kk + k][1];
                const float4 x = *reinterpret_cast<const float4*>(rows + k * Hh + lane * 4);
                acc[0] = fmaf(w, (x.x - mu) * rstd * g4.x + b4.x, acc[0]);
                acc[1] = fmaf(w, (x.y - mu) * rstd * g4.y + b4.y, acc[1]);
                acc[2] = fmaf(w, (x.z - mu) * rstd * g4.z + b4.z, acc[2]);
                acc[3] = fmaf(w, (x.w - mu) * rstd * g4.w + b4.w, acc[3]);
            }
            // ballot-compressed query rectification; scalars via readlane (VALU)
            unsigned long long mask = __ballot(lane < QT && myc == n);
            while (mask) {
                const int q = __ffsll(mask) - 1;
                mask &= mask - 1;
                const float w    = rdlane(myw,  q);
                const float mu   = rdlane(mymu, q);
                const float rstd = rdlane(myr,  q);
                const float4 x = *reinterpret_cast<const float4*>(qryB + (size_t)q * Hh + lane * 4);
                acc[0] = fmaf(w, (x.x - mu) * rstd * g4.x + b4.x, acc[0]);
                acc[1] = fmaf(w, (x.y - mu) * rstd * g4.y + b4.y, acc[1]);
                acc[2] = fmaf(w, (x.z - mu) * rstd * g4.z + b4.z, acc[2]);
                acc[3] = fmaf(w, (x.w - mu) * rstd * g4.w + b4.w, acc[3]);
            }
            const float inv = 1.0f / (float)(Kk + cnt_s[n]);
            float pv[4];
#pragma unroll
            for (int i = 0; i < 4; ++i) pv[i] = acc[i] * inv;
            *reinterpret_cast<float4*>(&proto_s[n][lane * 4]) =
                make_float4(pv[0], pv[1], pv[2], pv[3]);
            float pp = pv[0] * pv[0];
            pp = fmaf(pv[1], pv[1], pp); pp = fmaf(pv[2], pv[2], pp); pp = fmaf(pv[3], pv[3], pp);
            pp = sum64_lane63(pp);
            if (lane == 63) np_s[n] = pp;
        }
    }
    __syncthreads();

    // ---------------- F: groups 0-31, queries q = grp, grp+32 ----------------
    {
        const float npv = (lane < Nn) ? np_s[lane] : 0.f;
#pragma unroll
        for (int it = 0; it < 2; ++it) {
            const int q = grp + it * 32;
            if (q < QT) {
                const float* row  = qryB + (size_t)q * Hh;
                const float  mu   = qstat_s[q][0];
                const float  rstd = qstat_s[q][1];
                float y16[16];
#pragma unroll
                for (int c = 0; c < 4; ++c) {
                    const int h = c * 64 + sub * 4;
                    const float4 x  = *reinterpret_cast<const float4*>(row + h);
                    const float4 gg = *reinterpret_cast<const float4*>(g_s + h);
                    const float4 bb = *reinterpret_cast<const float4*>(bt_s + h);
                    y16[c * 4 + 0] = (x.x - mu) * rstd * gg.x + bb.x;
                    y16[c * 4 + 1] = (x.y - mu) * rstd * gg.y + bb.y;
                    y16[c * 4 + 2] = (x.z - mu) * rstd * gg.z + bb.z;
                    y16[c * 4 + 3] = (x.w - mu) * rstd * gg.w + bb.w;
                }
                const float ny = ny_s[q];

                float ov = 0.f, maxd = -INFINITY, bestd = INFINITY;
                int bestn = 0;
#pragma unroll
                for (int n = 0; n < Nn; ++n) {
                    float p = 0.f;
#pragma unroll
                    for (int c = 0; c < 4; ++c) {
                        const float4 pv = *reinterpret_cast<const float4*>(&proto_s[n][c * 64 + sub * 4]);
                        p = fmaf(y16[c * 4 + 0], pv.x, p);
                        p = fmaf(y16[c * 4 + 1], pv.y, p);
                        p = fmaf(y16[c * 4 + 2], pv.z, p);
                        p = fmaf(y16[c * 4 + 3], pv.w, p);
                    }
                    p = sum16_bcast(p);
                    const float d = ny + rdlane(npv, n) - 2.0f * p;
                    if (sub == n) ov = d;             // group-uniform d, cndmask
                    maxd = fmaxf(maxd, d);
                    if (d < bestd) { bestd = d; bestn = n; }
                }
                if (sub == Nn) ov = maxd + 1.0f;      // slot N: min(logits) - 1
                float* o = out + ((size_t)b * QT + q) * NP1;
                if (sub <= Nn) o[sub] = -ov;
                if (sub == Nn + 1)
                    out[(size_t)B * QT * NP1 + (size_t)b * QT + q] = (float)bestn;
            }
        }
    }
}

extern "C" void kernel_launch(void* const* d_in, const int* in_sizes, int n_in,
                              void* d_out, int out_size, void* d_ws, size_t ws_size,
                              hipStream_t stream) {
    const float* support = (const float*)d_in[0];
    const float* query   = (const float*)d_in[1];
    const float* gamma   = (const float*)d_in[2];
    const float* beta    = (const float*)d_in[3];
    float* out = (float*)d_out;

    const int B = in_sizes[0] / (Nn * Kk * Hh);   // 512
    proto_rectify_fused<<<B, 512, 0, stream>>>(support, query, gamma, beta, out, B);
}

// Round 12
// 29.313 us; speedup vs baseline: 1.5365x; 1.1264x over previous
//
#include <hip/hip_runtime.h>
#include <math.h>

#define LN_EPS 1e-5f

// Problem constants (fixed by setup_inputs): N=10, K=5, Q=5, H=256, Qtot=50
constexpr int Nn  = 10;
constexpr int Kk  = 5;
constexpr int Hh  = 256;
constexpr int QT  = 50;
constexpr int NP1 = 11;

// ---------- DPP-based reductions (VALU pipe; zero DS-pipe ops) ----------
template<int CTRL, int RM>
__device__ __forceinline__ float dpp_term(float x) {
    return __int_as_float(__builtin_amdgcn_update_dpp(
        0, __float_as_int(x), CTRL, RM, 0xf, true));   // bound_ctrl: OOB -> 0
}
// broadcast sum across each 16-lane group (4 DPP adds)
__device__ __forceinline__ float sum16_bcast(float v) {
    v += dpp_term<0xB1,  0xf>(v);   // quad_perm [1,0,3,2]
    v += dpp_term<0x4E,  0xf>(v);   // quad_perm [2,3,0,1]
    v += dpp_term<0x124, 0xf>(v);   // row_ror:4
    v += dpp_term<0x128, 0xf>(v);   // row_ror:8 -> full 16-sum, all lanes
    return v;
}
// wave sum accumulated into lane 63 (6 DPP adds)
__device__ __forceinline__ float sum64_lane63(float v) {
    v += dpp_term<0x111, 0xf>(v);   // row_shr:1
    v += dpp_term<0x112, 0xf>(v);   // row_shr:2
    v += dpp_term<0x114, 0xf>(v);   // row_shr:4
    v += dpp_term<0x118, 0xf>(v);   // row_shr:8
    v += dpp_term<0x142, 0xa>(v);   // row_bcast:15 -> rows 1,3
    v += dpp_term<0x143, 0xc>(v);   // row_bcast:31 -> rows 2,3 (lane63 = total)
    return v;
}
__device__ __forceinline__ float rdlane(float v, int l) {
    return __int_as_float(__builtin_amdgcn_readlane(__float_as_int(v), l));
}
__device__ __forceinline__ float wave64_sum_bcast(float v) {
    return rdlane(sum64_lane63(v), 63);
}

// 16-lane-group dot of y16 vs an LDS row, ILP-4: 4 independent 4-fma chains
// (one per c sub-block) + 2-level tree. Critical depth ~10 vs ~20 serial.
__device__ __forceinline__ float dot16_ilp4(const float y16[16],
                                            const float* __restrict__ rowbase,
                                            int sub) {
    float p0, p1, p2, p3;
    {
        const float4 v = *reinterpret_cast<const float4*>(rowbase + 0 * 64 + sub * 4);
        p0 = y16[0] * v.x; p0 = fmaf(y16[1], v.y, p0);
        p0 = fmaf(y16[2], v.z, p0); p0 = fmaf(y16[3], v.w, p0);
    }
    {
        const float4 v = *reinterpret_cast<const float4*>(rowbase + 1 * 64 + sub * 4);
        p1 = y16[4] * v.x; p1 = fmaf(y16[5], v.y, p1);
        p1 = fmaf(y16[6], v.z, p1); p1 = fmaf(y16[7], v.w, p1);
    }
    {
        const float4 v = *reinterpret_cast<const float4*>(rowbase + 2 * 64 + sub * 4);
        p2 = y16[8] * v.x; p2 = fmaf(y16[9], v.y, p2);
        p2 = fmaf(y16[10], v.z, p2); p2 = fmaf(y16[11], v.w, p2);
    }
    {
        const float4 v = *reinterpret_cast<const float4*>(rowbase + 3 * 64 + sub * 4);
        p3 = y16[12] * v.x; p3 = fmaf(y16[13], v.y, p3);
        p3 = fmaf(y16[14], v.z, p3); p3 = fmaf(y16[15], v.w, p3);
    }
    return (p0 + p1) + (p2 + p3);
}

// One batch per 1024-thread block (16 waves). 3 barriers.
// Round-8 structure (28.6us proven) + latency fixes:
//   - ILP-4 dot chains in C/F (4 partial accumulators, tree combine)
//   - ILP-4 LN stats chains in C
//   - nM/np hoisted to registers via readlane (no per-n ds_read in compare chain)
// A  (waves 0-9):  support stream: LN inline (stats->LDS), M, ||M||^2, scores.
// C  (groups 0-49): fused LN stats, ny->LDS, argmin(nM-2p), wq/cq/counts.
//     B (groups 56-60): per-k softmax over N of support scores.
// E  (waves 0-9):  rectified prototype (ballot loop, readlane bcast), ||p||^2.
// F  (groups 0-49): reload+LN from qstat, d=ny+np-2p, logits+pred.
// NOTE: nothing register-live across barriers (round-4 spill lesson).
__global__ __launch_bounds__(1024, 8) void proto_rectify_fused(
    const float* __restrict__ support, const float* __restrict__ query,
    const float* __restrict__ gamma,   const float* __restrict__ beta,
    float* __restrict__ out, int B)
{
    const int b    = blockIdx.x;
    const int tid  = threadIdx.x;
    const int lane = tid & 63;
    const int wave = tid >> 6;   // 0..15
    const int grp  = tid >> 4;   // 0..63
    const int sub  = tid & 15;

    __shared__ float g_s[Hh], bt_s[Hh];
    __shared__ float M_s[Nn][Hh];
    __shared__ float proto_s[Nn][Hh];
    __shared__ float nM_s[Nn], np_s[Nn];
    __shared__ float ny_s[QT];
    __shared__ float score_s[Nn * Kk];
    __shared__ float wsup_s[Nn * Kk];
    __shared__ float wq_s[QT];
    __shared__ int   cq_s[QT];
    __shared__ float sstat_s[Nn * Kk][2];  // support row: mu, rstd
    __shared__ float qstat_s[QT][2];       // query row:   mu, rstd
    __shared__ int   cnt_s[Nn];

    const float* supB = support + (size_t)b * (Nn * Kk * Hh);
    const float* qryB = query   + (size_t)b * (QT * Hh);

    // LDS preload runs concurrently with phase A (consumed only after sync 1)
    if (tid < Hh)          g_s[tid]       = gamma[tid];
    else if (tid < 2 * Hh) bt_s[tid - Hh] = beta[tid - Hh];
    if (tid < Nn)          cnt_s[tid]     = 0;

    // ---------------- Phase A: support only (waves 0-9) ----------------
    if (wave < Nn) {
        const int n = wave;
        const float4 g4 = *reinterpret_cast<const float4*>(gamma + lane * 4); // L1
        const float4 b4 = *reinterpret_cast<const float4*>(beta  + lane * 4);
        const float* rows = supB + (size_t)n * Kk * Hh;

        float y[Kk][4];
#pragma unroll
        for (int k = 0; k < Kk; ++k) {
            const float4 x = *reinterpret_cast<const float4*>(rows + k * Hh + lane * 4);
            float s  = x.x + x.y + x.z + x.w;
            float ss = x.x * x.x + x.y * x.y + x.z * x.z + x.w * x.w;
            s  = wave64_sum_bcast(s);
            ss = wave64_sum_bcast(ss);
            const float mu   = s * (1.0f / (float)Hh);
            const float rstd = rsqrtf(ss * (1.0f / (float)Hh) - mu * mu + LN_EPS);
            if (lane == 0) { sstat_s[n * Kk + k][0] = mu; sstat_s[n * Kk + k][1] = rstd; }
            y[k][0] = (x.x - mu) * rstd * g4.x + b4.x;
            y[k][1] = (x.y - mu) * rstd * g4.y + b4.y;
            y[k][2] = (x.z - mu) * rstd * g4.z + b4.z;
            y[k][3] = (x.w - mu) * rstd * g4.w + b4.w;
        }
        float Mv[4];
#pragma unroll
        for (int i = 0; i < 4; ++i)
            Mv[i] = (y[0][i] + y[1][i] + y[2][i] + y[3][i] + y[4][i]) / 5.0f;
        *reinterpret_cast<float4*>(&M_s[n][lane * 4]) =
            make_float4(Mv[0], Mv[1], Mv[2], Mv[3]);

        float pm = Mv[0] * Mv[0];
        pm = fmaf(Mv[1], Mv[1], pm); pm = fmaf(Mv[2], Mv[2], pm); pm = fmaf(Mv[3], Mv[3], pm);
        pm = sum64_lane63(pm);
        if (lane == 63) nM_s[n] = pm;

#pragma unroll
        for (int k = 0; k < Kk; ++k) {
            float p = y[k][0] * Mv[0];
            p = fmaf(y[k][1], Mv[1], p); p = fmaf(y[k][2], Mv[2], p); p = fmaf(y[k][3], Mv[3], p);
            p = sum64_lane63(p);
            if (lane == 63) score_s[n * Kk + k] = p;
        }
    }
    __syncthreads();

    // ---------------- C (groups 0-49, fused LN stats) + B (groups 56-60) -----
    if (grp < QT) {
        const int q = grp;
        const float* row = qryB + (size_t)q * Hh;
        const float nmv = (lane < Nn) ? nM_s[lane] : 0.f;   // hoist ||M||^2
        float y16[16];
        float s0 = 0.f, s1 = 0.f, s2 = 0.f, s3 = 0.f;
        float t0 = 0.f, t1 = 0.f, t2 = 0.f, t3 = 0.f;
        {
            const float4 x = *reinterpret_cast<const float4*>(row + 0 * 64 + sub * 4);
            y16[0] = x.x; y16[1] = x.y; y16[2] = x.z; y16[3] = x.w;
            s0 = x.x + x.y + x.z + x.w;
            t0 = fmaf(x.x, x.x, fmaf(x.y, x.y, fmaf(x.z, x.z, x.w * x.w)));
        }
        {
            const float4 x = *reinterpret_cast<const float4*>(row + 1 * 64 + sub * 4);
            y16[4] = x.x; y16[5] = x.y; y16[6] = x.z; y16[7] = x.w;
            s1 = x.x + x.y + x.z + x.w;
            t1 = fmaf(x.x, x.x, fmaf(x.y, x.y, fmaf(x.z, x.z, x.w * x.w)));
        }
        {
            const float4 x = *reinterpret_cast<const float4*>(row + 2 * 64 + sub * 4);
            y16[8] = x.x; y16[9] = x.y; y16[10] = x.z; y16[11] = x.w;
            s2 = x.x + x.y + x.z + x.w;
            t2 = fmaf(x.x, x.x, fmaf(x.y, x.y, fmaf(x.z, x.z, x.w * x.w)));
        }
        {
            const float4 x = *reinterpret_cast<const float4*>(row + 3 * 64 + sub * 4);
            y16[12] = x.x; y16[13] = x.y; y16[14] = x.z; y16[15] = x.w;
            s3 = x.x + x.y + x.z + x.w;
            t3 = fmaf(x.x, x.x, fmaf(x.y, x.y, fmaf(x.z, x.z, x.w * x.w)));
        }
        float s  = sum16_bcast((s0 + s1) + (s2 + s3));
        float ss = sum16_bcast((t0 + t1) + (t2 + t3));
        const float mu   = s * (1.0f / (float)Hh);
        const float rstd = rsqrtf(ss * (1.0f / (float)Hh) - mu * mu + LN_EPS);
        if (sub == 0) { qstat_s[q][0] = mu; qstat_s[q][1] = rstd; }

#pragma unroll
        for (int c = 0; c < 4; ++c) {
            const int h = c * 64 + sub * 4;
            const float4 gg = *reinterpret_cast<const float4*>(g_s + h);
            const float4 bb = *reinterpret_cast<const float4*>(bt_s + h);
            y16[c * 4 + 0] = (y16[c * 4 + 0] - mu) * rstd * gg.x + bb.x;
            y16[c * 4 + 1] = (y16[c * 4 + 1] - mu) * rstd * gg.y + bb.y;
            y16[c * 4 + 2] = (y16[c * 4 + 2] - mu) * rstd * gg.z + bb.z;
            y16[c * 4 + 3] = (y16[c * 4 + 3] - mu) * rstd * gg.w + bb.w;
        }
        float n0 = fmaf(y16[0], y16[0], fmaf(y16[1], y16[1],
                   fmaf(y16[2], y16[2], y16[3] * y16[3])));
        float n1 = fmaf(y16[4], y16[4], fmaf(y16[5], y16[5],
                   fmaf(y16[6], y16[6], y16[7] * y16[7])));
        float n2 = fmaf(y16[8], y16[8], fmaf(y16[9], y16[9],
                   fmaf(y16[10], y16[10], y16[11] * y16[11])));
        float n3 = fmaf(y16[12], y16[12], fmaf(y16[13], y16[13],
                   fmaf(y16[14], y16[14], y16[15] * y16[15])));
        float ny = sum16_bcast((n0 + n1) + (n2 + n3));
        if (sub == 0) ny_s[q] = ny;

        // argmin_n (ny + nM - 2p) == argmin_n (nM - 2p): ny is constant per q
        float bestd = INFINITY, bestdot = 0.f;
        int bestn = 0;
#pragma unroll
        for (int n = 0; n < Nn; ++n) {
            float p = dot16_ilp4(y16, &M_s[n][0], sub);
            p = sum16_bcast(p);
            const float d = rdlane(nmv, n) - 2.0f * p;
            if (d < bestd) { bestd = d; bestn = n; bestdot = p; }  // first-min tie-break
        }
        if (sub == 0) {
            const float sc  = bestdot;             // <q, M_bestn>
            const float mx  = fmaxf(sc, 0.f);
            const float e   = expf(sc - mx);
            const float den = e + (float)(Nn - 1) * expf(-mx);
            wq_s[q] = e / den;
            cq_s[q] = bestn;
            atomicAdd(&cnt_s[bestn], 1);
        }
    } else if (grp >= 56 && grp < 56 + Kk && sub == 0) {
        const int k = grp - 56;
        float mx = -INFINITY;
#pragma unroll
        for (int n = 0; n < Nn; ++n) mx = fmaxf(mx, score_s[n * Kk + k]);
        float e[Nn]; float den = 0.f;
#pragma unroll
        for (int n = 0; n < Nn; ++n) { e[n] = expf(score_s[n * Kk + k] - mx); den += e[n]; }
#pragma unroll
        for (int n = 0; n < Nn; ++n) wsup_s[n * Kk + k] = e[n] / den;
    }
    __syncthreads();

    // ---------------- E (waves 0-9): rectified prototype ----------------
    if (wave < Nn) {
        const int n = wave;
        const float4 g4 = *reinterpret_cast<const float4*>(g_s  + lane * 4);
        const float4 b4 = *reinterpret_cast<const float4*>(bt_s + lane * 4);
        const float* rows = supB + (size_t)n * Kk * Hh;

        float acc[4] = {0.f, 0.f, 0.f, 0.f};
#pragma unroll
        for (int k = 0; k < Kk; ++k) {
            const float w    = wsup_s[n * Kk + k];
            const float mu   = sstat_s[n * Kk + k][0];
            const float rstd = sstat_s[n * Kk + k][1];
            const float4 x = *reinterpret_cast<const float4*>(rows + k * Hh + lane * 4);
            acc[0] = fmaf(w, (x.x - mu) * rstd * g4.x + b4.x, acc[0]);
            acc[1] = fmaf(w, (x.y - mu) * rstd * g4.y + b4.y, acc[1]);
            acc[2] = fmaf(w, (x.z - mu) * rstd * g4.z + b4.z, acc[2]);
            acc[3] = fmaf(w, (x.w - mu) * rstd * g4.w + b4.w, acc[3]);
        }
        // ballot-compressed query rectification; per-q scalars via readlane (VALU)
        int myc = -1; float myw = 0.f, mymu = 0.f, myr = 0.f;
        if (lane < QT) {
            myc  = cq_s[lane]; myw = wq_s[lane];
            mymu = qstat_s[lane][0]; myr = qstat_s[lane][1];
        }
        unsigned long long mask = __ballot(lane < QT && myc == n);
        while (mask) {
            const int q = __ffsll(mask) - 1;
            mask &= mask - 1;
            const float w    = rdlane(myw,  q);
            const float mu   = rdlane(mymu, q);
            const float rstd = rdlane(myr,  q);
            const float4 x = *reinterpret_cast<const float4*>(qryB + (size_t)q * Hh + lane * 4);
            acc[0] = fmaf(w, (x.x - mu) * rstd * g4.x + b4.x, acc[0]);
            acc[1] = fmaf(w, (x.y - mu) * rstd * g4.y + b4.y, acc[1]);
            acc[2] = fmaf(w, (x.z - mu) * rstd * g4.z + b4.z, acc[2]);
            acc[3] = fmaf(w, (x.w - mu) * rstd * g4.w + b4.w, acc[3]);
        }
        const float inv = 1.0f / (float)(Kk + cnt_s[n]);
        float pv[4];
#pragma unroll
        for (int i = 0; i < 4; ++i) pv[i] = acc[i] * inv;
        *reinterpret_cast<float4*>(&proto_s[n][lane * 4]) =
            make_float4(pv[0], pv[1], pv[2], pv[3]);
        float pp = pv[0] * pv[0];
        pp = fmaf(pv[1], pv[1], pp); pp = fmaf(pv[2], pv[2], pp); pp = fmaf(pv[3], pv[3], pp);
        pp = sum64_lane63(pp);
        if (lane == 63) np_s[n] = pp;
    }
    __syncthreads();

    // ---------------- F (groups 0-49): logits + pred ----------------
    if (grp < QT) {
        const int q = grp;
        const float* row  = qryB + (size_t)q * Hh;
        const float  mu   = qstat_s[q][0];
        const float  rstd = qstat_s[q][1];
        const float  npv  = (lane < Nn) ? np_s[lane] : 0.f;   // hoist ||p||^2
        float y16[16];
#pragma unroll
        for (int c = 0; c < 4; ++c) {
            const int h = c * 64 + sub * 4;
            const float4 x  = *reinterpret_cast<const float4*>(row + h);
            const float4 gg = *reinterpret_cast<const float4*>(g_s + h);
            const float4 bb = *reinterpret_cast<const float4*>(bt_s + h);
            y16[c * 4 + 0] = (x.x - mu) * rstd * gg.x + bb.x;
            y16[c * 4 + 1] = (x.y - mu) * rstd * gg.y + bb.y;
            y16[c * 4 + 2] = (x.z - mu) * rstd * gg.z + bb.z;
            y16[c * 4 + 3] = (x.w - mu) * rstd * gg.w + bb.w;
        }
        const float ny = ny_s[q];

        float mine = 0.f, maxd = -INFINITY, bestd = INFINITY;
        int bestn = 0;
#pragma unroll
        for (int n = 0; n < Nn; ++n) {
            float p = dot16_ilp4(y16, &proto_s[n][0], sub);
            p = sum16_bcast(p);
            const float d = ny + rdlane(npv, n) - 2.0f * p;
            if (sub == n) mine = d;
            maxd = fmaxf(maxd, d);
            if (d < bestd) { bestd = d; bestn = n; }
        }
        float* o = out + ((size_t)b * QT + q) * NP1;
        if (sub < Nn)       o[sub] = -mine;
        else if (sub == Nn) o[Nn]  = -maxd - 1.0f;             // min(logits) - 1
        else if (sub == Nn + 1)
            out[(size_t)B * QT * NP1 + (size_t)b * QT + q] = (float)bestn;
    }
}

extern "C" void kernel_launch(void* const* d_in, const int* in_sizes, int n_in,
                              void* d_out, int out_size, void* d_ws, size_t ws_size,
                              hipStream_t stream) {
    const float* support = (const float*)d_in[0];
    const float* query   = (const float*)d_in[1];
    const float* gamma   = (const float*)d_in[2];
    const float* beta    = (const float*)d_in[3];
    float* out = (float*)d_out;

    const int B = in_sizes[0] / (Nn * Kk * Hh);   // 512
    proto_rectify_fused<<<B, 1024, 0, stream>>>(support, query, gamma, beta, out, B);
}

// Round 13
// 25.735 us; speedup vs baseline: 1.7501x; 1.1390x over previous
//
#include <hip/hip_runtime.h>
#include <math.h>

#define LN_EPS 1e-5f

// Problem constants (fixed by setup_inputs): N=10, K=5, Q=5, H=256, Qtot=50
constexpr int Nn  = 10;
constexpr int Kk  = 5;
constexpr int Hh  = 256;
constexpr int QT  = 50;
constexpr int NP1 = 11;

// ---------- DPP-based reductions (VALU pipe; zero DS-pipe ops) ----------
template<int CTRL, int RM>
__device__ __forceinline__ float dpp_term(float x) {
    return __int_as_float(__builtin_amdgcn_update_dpp(
        0, __float_as_int(x), CTRL, RM, 0xf, true));   // bound_ctrl: OOB -> 0
}
// broadcast sum across each 16-lane group (4 DPP adds)
__device__ __forceinline__ float sum16_bcast(float v) {
    v += dpp_term<0xB1,  0xf>(v);   // quad_perm [1,0,3,2]
    v += dpp_term<0x4E,  0xf>(v);   // quad_perm [2,3,0,1]
    v += dpp_term<0x124, 0xf>(v);   // row_ror:4
    v += dpp_term<0x128, 0xf>(v);   // row_ror:8 -> full 16-sum, all lanes
    return v;
}
// wave sum accumulated into lane 63 (6 DPP adds)
__device__ __forceinline__ float sum64_lane63(float v) {
    v += dpp_term<0x111, 0xf>(v);   // row_shr:1
    v += dpp_term<0x112, 0xf>(v);   // row_shr:2
    v += dpp_term<0x114, 0xf>(v);   // row_shr:4
    v += dpp_term<0x118, 0xf>(v);   // row_shr:8
    v += dpp_term<0x142, 0xa>(v);   // row_bcast:15 -> rows 1,3
    v += dpp_term<0x143, 0xc>(v);   // row_bcast:31 -> rows 2,3 (lane63 = total)
    return v;
}
__device__ __forceinline__ float rdlane(float v, int l) {
    return __int_as_float(__builtin_amdgcn_readlane(__float_as_int(v), l));
}
__device__ __forceinline__ float wave64_sum_bcast(float v) {
    return rdlane(sum64_lane63(v), 63);
}

// 16-lane-group dot of y16 vs an LDS row, ILP-4 (4 independent chains + tree)
__device__ __forceinline__ float dot16_ilp4(const float y16[16],
                                            const float* __restrict__ rowbase,
                                            int sub) {
    float p0, p1, p2, p3;
    {
        const float4 v = *reinterpret_cast<const float4*>(rowbase + 0 * 64 + sub * 4);
        p0 = y16[0] * v.x; p0 = fmaf(y16[1], v.y, p0);
        p0 = fmaf(y16[2], v.z, p0); p0 = fmaf(y16[3], v.w, p0);
    }
    {
        const float4 v = *reinterpret_cast<const float4*>(rowbase + 1 * 64 + sub * 4);
        p1 = y16[4] * v.x; p1 = fmaf(y16[5], v.y, p1);
        p1 = fmaf(y16[6], v.z, p1); p1 = fmaf(y16[7], v.w, p1);
    }
    {
        const float4 v = *reinterpret_cast<const float4*>(rowbase + 2 * 64 + sub * 4);
        p2 = y16[8] * v.x; p2 = fmaf(y16[9], v.y, p2);
        p2 = fmaf(y16[10], v.z, p2); p2 = fmaf(y16[11], v.w, p2);
    }
    {
        const float4 v = *reinterpret_cast<const float4*>(rowbase + 3 * 64 + sub * 4);
        p3 = y16[12] * v.x; p3 = fmaf(y16[13], v.y, p3);
        p3 = fmaf(y16[14], v.z, p3); p3 = fmaf(y16[15], v.w, p3);
    }
    return (p0 + p1) + (p2 + p3);
}

// One batch per 1024-thread block (16 waves). 3 barriers.
// All HBM streaming concentrated in phase A (16/16 waves loading):
// A  (waves 0-9):  support stream: LN inline (sstat->LDS), M->MP_s, ||M||^2,
//                  support scores.
// A' (waves 10-15): query stream: LN stats (wave64 DPP), LN'd y -> qy_s LDS,
//                  ||y||^2 -> ny_s. (Previously idle waves; removes all global
//                  query loads + LN work from C/E/F.)
// C  (groups 0-49): y16 from qy_s (4x ds_read_b128, conflict-free), dots vs M
//                  (ILP-4 + sum16), argmin(nM-2p), wq/cq/counts.
//     B (groups 56-60): per-k softmax over N of support scores.
// E  (waves 0-9):  rectified prototype; ballot loop reads LN'd y from qy_s;
//                  proto written INTO MP_s (M dead after C); ||p||^2.
// F  (groups 0-49): y16 from qy_s, dots vs proto(MP_s), logits+pred.
// LDS ~63KB/block (qy 51.2K + MP 10.2K + small) -> still 2 blocks/CU.
// NOTE: nothing register-live across barriers (round-4 spill lesson).
__global__ __launch_bounds__(1024, 8) void proto_rectify_fused(
    const float* __restrict__ support, const float* __restrict__ query,
    const float* __restrict__ gamma,   const float* __restrict__ beta,
    float* __restrict__ out, int B)
{
    const int b    = blockIdx.x;
    const int tid  = threadIdx.x;
    const int lane = tid & 63;
    const int wave = tid >> 6;   // 0..15
    const int grp  = tid >> 4;   // 0..63
    const int sub  = tid & 15;

    __shared__ float qy_s[QT][Hh];        // LN'd query rows (51.2 KB)
    __shared__ float MP_s[Nn][Hh];        // M (A-C), then proto (E-F)
    __shared__ float nM_s[Nn], np_s[Nn];
    __shared__ float ny_s[QT];
    __shared__ float score_s[Nn * Kk];
    __shared__ float wsup_s[Nn * Kk];
    __shared__ float wq_s[QT];
    __shared__ int   cq_s[QT];
    __shared__ float sstat_s[Nn * Kk][2]; // support row: mu, rstd
    __shared__ int   cnt_s[Nn];

    const float* supB = support + (size_t)b * (Nn * Kk * Hh);
    const float* qryB = query   + (size_t)b * (QT * Hh);

    if (tid < Nn) cnt_s[tid] = 0;

    // ---------------- Phase A / A' ----------------
    const float4 g4 = *reinterpret_cast<const float4*>(gamma + lane * 4);  // L1
    const float4 b4 = *reinterpret_cast<const float4*>(beta  + lane * 4);
    if (wave < Nn) {
        const int n = wave;
        const float* rows = supB + (size_t)n * Kk * Hh;

        float y[Kk][4];
#pragma unroll
        for (int k = 0; k < Kk; ++k) {
            const float4 x = *reinterpret_cast<const float4*>(rows + k * Hh + lane * 4);
            float s  = x.x + x.y + x.z + x.w;
            float ss = x.x * x.x + x.y * x.y + x.z * x.z + x.w * x.w;
            s  = wave64_sum_bcast(s);
            ss = wave64_sum_bcast(ss);
            const float mu   = s * (1.0f / (float)Hh);
            const float rstd = rsqrtf(ss * (1.0f / (float)Hh) - mu * mu + LN_EPS);
            if (lane == 0) { sstat_s[n * Kk + k][0] = mu; sstat_s[n * Kk + k][1] = rstd; }
            y[k][0] = (x.x - mu) * rstd * g4.x + b4.x;
            y[k][1] = (x.y - mu) * rstd * g4.y + b4.y;
            y[k][2] = (x.z - mu) * rstd * g4.z + b4.z;
            y[k][3] = (x.w - mu) * rstd * g4.w + b4.w;
        }
        float Mv[4];
#pragma unroll
        for (int i = 0; i < 4; ++i)
            Mv[i] = (y[0][i] + y[1][i] + y[2][i] + y[3][i] + y[4][i]) / 5.0f;
        *reinterpret_cast<float4*>(&MP_s[n][lane * 4]) =
            make_float4(Mv[0], Mv[1], Mv[2], Mv[3]);

        float pm = Mv[0] * Mv[0];
        pm = fmaf(Mv[1], Mv[1], pm); pm = fmaf(Mv[2], Mv[2], pm); pm = fmaf(Mv[3], Mv[3], pm);
        pm = sum64_lane63(pm);
        if (lane == 63) nM_s[n] = pm;

#pragma unroll
        for (int k = 0; k < Kk; ++k) {
            float p = y[k][0] * Mv[0];
            p = fmaf(y[k][1], Mv[1], p); p = fmaf(y[k][2], Mv[2], p); p = fmaf(y[k][3], Mv[3], p);
            p = sum64_lane63(p);
            if (lane == 63) score_s[n * Kk + k] = p;
        }
    } else {
        // A': waves 10-15 stream + LN all 50 query rows into qy_s
        for (int r = wave - 10; r < QT; r += 6) {
            const float4 x = *reinterpret_cast<const float4*>(
                qryB + (size_t)r * Hh + lane * 4);
            float s  = x.x + x.y + x.z + x.w;
            float ss = fmaf(x.x, x.x, fmaf(x.y, x.y, fmaf(x.z, x.z, x.w * x.w)));
            s  = wave64_sum_bcast(s);
            ss = wave64_sum_bcast(ss);
            const float mu   = s * (1.0f / (float)Hh);
            const float rstd = rsqrtf(ss * (1.0f / (float)Hh) - mu * mu + LN_EPS);
            float y0 = (x.x - mu) * rstd * g4.x + b4.x;
            float y1 = (x.y - mu) * rstd * g4.y + b4.y;
            float y2 = (x.z - mu) * rstd * g4.z + b4.z;
            float y3 = (x.w - mu) * rstd * g4.w + b4.w;
            *reinterpret_cast<float4*>(&qy_s[r][lane * 4]) =
                make_float4(y0, y1, y2, y3);
            float ny = fmaf(y0, y0, fmaf(y1, y1, fmaf(y2, y2, y3 * y3)));
            ny = sum64_lane63(ny);
            if (lane == 63) ny_s[r] = ny;
        }
    }
    __syncthreads();

    // ---------------- C (groups 0-49) + B (groups 56-60) ----------------
    if (grp < QT) {
        const int q = grp;
        const float nmv = (lane < Nn) ? nM_s[lane] : 0.f;   // hoist ||M||^2
        float y16[16];
#pragma unroll
        for (int c = 0; c < 4; ++c) {
            const float4 v = *reinterpret_cast<const float4*>(&qy_s[q][c * 64 + sub * 4]);
            y16[c * 4 + 0] = v.x; y16[c * 4 + 1] = v.y;
            y16[c * 4 + 2] = v.z; y16[c * 4 + 3] = v.w;
        }
        float bestd = INFINITY, bestdot = 0.f;
        int bestn = 0;
#pragma unroll
        for (int n = 0; n < Nn; ++n) {
            float p = dot16_ilp4(y16, &MP_s[n][0], sub);
            p = sum16_bcast(p);
            const float d = rdlane(nmv, n) - 2.0f * p;   // argmin drops ny (const/q)
            if (d < bestd) { bestd = d; bestn = n; bestdot = p; }  // first-min tie-break
        }
        if (sub == 0) {
            const float sc  = bestdot;             // <q, M_bestn>
            const float mx  = fmaxf(sc, 0.f);
            const float e   = expf(sc - mx);
            const float den = e + (float)(Nn - 1) * expf(-mx);
            wq_s[q] = e / den;
            cq_s[q] = bestn;
            atomicAdd(&cnt_s[bestn], 1);
        }
    } else if (grp >= 56 && grp < 56 + Kk && sub == 0) {
        const int k = grp - 56;
        float mx = -INFINITY;
#pragma unroll
        for (int n = 0; n < Nn; ++n) mx = fmaxf(mx, score_s[n * Kk + k]);
        float e[Nn]; float den = 0.f;
#pragma unroll
        for (int n = 0; n < Nn; ++n) { e[n] = expf(score_s[n * Kk + k] - mx); den += e[n]; }
#pragma unroll
        for (int n = 0; n < Nn; ++n) wsup_s[n * Kk + k] = e[n] / den;
    }
    __syncthreads();

    // ---------------- E (waves 0-9): rectified prototype -> MP_s ----------------
    if (wave < Nn) {
        const int n = wave;
        const float* rows = supB + (size_t)n * Kk * Hh;

        float acc[4] = {0.f, 0.f, 0.f, 0.f};
#pragma unroll
        for (int k = 0; k < Kk; ++k) {
            const float w    = wsup_s[n * Kk + k];
            const float mu   = sstat_s[n * Kk + k][0];
            const float rstd = sstat_s[n * Kk + k][1];
            const float4 x = *reinterpret_cast<const float4*>(rows + k * Hh + lane * 4);
            acc[0] = fmaf(w, (x.x - mu) * rstd * g4.x + b4.x, acc[0]);
            acc[1] = fmaf(w, (x.y - mu) * rstd * g4.y + b4.y, acc[1]);
            acc[2] = fmaf(w, (x.z - mu) * rstd * g4.z + b4.z, acc[2]);
            acc[3] = fmaf(w, (x.w - mu) * rstd * g4.w + b4.w, acc[3]);
        }
        // ballot-compressed query rectification; LN'd y read from qy_s (LDS)
        int myc = -1; float myw = 0.f;
        if (lane < QT) { myc = cq_s[lane]; myw = wq_s[lane]; }
        unsigned long long mask = __ballot(lane < QT && myc == n);
        while (mask) {
            const int q = __ffsll(mask) - 1;
            mask &= mask - 1;
            const float w = rdlane(myw, q);
            const float4 yv = *reinterpret_cast<const float4*>(&qy_s[q][lane * 4]);
            acc[0] = fmaf(w, yv.x, acc[0]);
            acc[1] = fmaf(w, yv.y, acc[1]);
            acc[2] = fmaf(w, yv.z, acc[2]);
            acc[3] = fmaf(w, yv.w, acc[3]);
        }
        const float inv = 1.0f / (float)(Kk + cnt_s[n]);
        float pv[4];
#pragma unroll
        for (int i = 0; i < 4; ++i) pv[i] = acc[i] * inv;
        *reinterpret_cast<float4*>(&MP_s[n][lane * 4]) =      // proto overwrites M
            make_float4(pv[0], pv[1], pv[2], pv[3]);
        float pp = pv[0] * pv[0];
        pp = fmaf(pv[1], pv[1], pp); pp = fmaf(pv[2], pv[2], pp); pp = fmaf(pv[3], pv[3], pp);
        pp = sum64_lane63(pp);
        if (lane == 63) np_s[n] = pp;
    }
    __syncthreads();

    // ---------------- F (groups 0-49): logits + pred ----------------
    if (grp < QT) {
        const int q = grp;
        const float npv = (lane < Nn) ? np_s[lane] : 0.f;    // hoist ||p||^2
        float y16[16];
#pragma unroll
        for (int c = 0; c < 4; ++c) {
            const float4 v = *reinterpret_cast<const float4*>(&qy_s[q][c * 64 + sub * 4]);
            y16[c * 4 + 0] = v.x; y16[c * 4 + 1] = v.y;
            y16[c * 4 + 2] = v.z; y16[c * 4 + 3] = v.w;
        }
        const float ny = ny_s[q];

        float mine = 0.f, maxd = -INFINITY, bestd = INFINITY;
        int bestn = 0;
#pragma unroll
        for (int n = 0; n < Nn; ++n) {
            float p = dot16_ilp4(y16, &MP_s[n][0], sub);     // proto
            p = sum16_bcast(p);
            const float d = ny + rdlane(npv, n) - 2.0f * p;
            if (sub == n) mine = d;
            maxd = fmaxf(maxd, d);
            if (d < bestd) { bestd = d; bestn = n; }
        }
        float* o = out + ((size_t)b * QT + q) * NP1;
        if (sub < Nn)       o[sub] = -mine;
        else if (sub == Nn) o[Nn]  = -maxd - 1.0f;           // min(logits) - 1
        else if (sub == Nn + 1)
            out[(size_t)B * QT * NP1 + (size_t)b * QT + q] = (float)bestn;
    }
}

extern "C" void kernel_launch(void* const* d_in, const int* in_sizes, int n_in,
                              void* d_out, int out_size, void* d_ws, size_t ws_size,
                              hipStream_t stream) {
    const float* support = (const float*)d_in[0];
    const float* query   = (const float*)d_in[1];
    const float* gamma   = (const float*)d_in[2];
    const float* beta    = (const float*)d_in[3];
    float* out = (float*)d_out;

    const int B = in_sizes[0] / (Nn * Kk * Hh);   // 512
    proto_rectify_fused<<<B, 1024, 0, stream>>>(support, query, gamma, beta, out, B);
}